// Round 4
// baseline (65.112 us; speedup 1.0000x reference)
//
#include <hip/hip_runtime.h>

// PatchExtractor: B=64, C=128, H=W=64, M=16 units/batch, n=15 patch size.
// Gather is integer-exact:
//   ix = y_cord + j - 7, iy = x_cord + i - 7   (reference swaps x/y coords)
//   valid = (0<=ix<64) && (0<=iy<64)
//   out[p][c][i][j] = valid ? x[b][c][iy][ix] : 0   for c in [0,128)
// in_bounds (ch 128): exact-rational analysis of all standard float chains
// (np-f32, np-f64, jax-f32, +-FMA) shows ZERO boundary flips (in_bounds==valid)
// -- but rounds 1-3 (which implemented exactly those) failed identically.
// The only chain producing flips is reciprocal-multiply division lowering
// (x/63 -> x*fl32(1/63), XLA algebraic simplification): csn error +2.0..2.2
// ulp for coord in [56,62] pushes grid past +1.0 at sample index 63.
// Flip set (robust under fusion style / lin-table variants, margin >=1.5 ulp):
//   in_bounds = 0 iff idx==63 && coord<=62 (per axis); coord==63 survives;
//   idx==0 side never flips (worst case +0.86 ulp, inside).

constexpr int NP   = 15;
constexpr int NPOS = NP * NP;     // 225
constexpr int CH   = 128;
constexpr int HH   = 64, WW = 64;
constexpr int PLANE = HH * WW;    // 4096
constexpr int SEGS = 4;
constexpr int CH_PER_SEG = CH / SEGS;  // 32

__global__ __launch_bounds__(256)
void patch_extract(const float* __restrict__ x,
                   const int* __restrict__ xcord,
                   const int* __restrict__ ycord,
                   float* __restrict__ out) {
  const int p   = blockIdx.x;     // patch id 0..1023 (= b*16 + m)
  const int seg = blockIdx.y;     // 0..3 channel segment
  const int b   = p >> 4;         // M = 16
  const int xs  = xcord[p];
  const int ys  = ycord[p];

  __shared__ int   soff[NPOS];    // src offset within a channel plane, -1 if masked
  __shared__ float sbnd[NPOS];    // in_bounds channel value
  const int t = threadIdx.x;
  if (t < NPOS) {
    const int i  = t / NP;
    const int j  = t - i * NP;
    const int ix = ys + j - 7;    // x index driven by y_cord (reference quirk)
    const int iy = xs + i - 7;    // y index driven by x_cord
    const bool v = ((unsigned)ix < (unsigned)WW) && ((unsigned)iy < (unsigned)HH);
    soff[t] = v ? (iy * WW + ix) : -1;

    // in_bounds: valid minus the reciprocal-multiply boundary flips
    const bool xflip = (ix == WW - 1) && (ys < WW - 1);  // grid_x > 1 by ~1.2 ulp
    const bool yflip = (iy == HH - 1) && (xs < HH - 1);  // grid_y > 1 by ~1.2 ulp
    sbnd[t] = (v && !xflip && !yflip) ? 1.0f : 0.0f;
  }
  __syncthreads();

  const float* __restrict__ xb = x + (size_t)b * (CH * PLANE);
  float* __restrict__ op = out + (size_t)p * ((CH + 1) * NPOS);

  const int e0 = seg * (CH_PER_SEG * NPOS);   // 7200 elems per segment
  const int e1 = e0 + CH_PER_SEG * NPOS;
  for (int e = e0 + t; e < e1; e += 256) {
    const int ch  = e / NPOS;                 // magic-mul div by 225
    const int pos = e - ch * NPOS;
    const int off = soff[pos];
    op[e] = (off >= 0) ? xb[ch * PLANE + off] : 0.0f;
  }

  // in_bounds channel (c = 128), written once (by segment 3)
  if (seg == SEGS - 1 && t < NPOS) {
    op[CH * NPOS + t] = sbnd[t];
  }
}

extern "C" void kernel_launch(void* const* d_in, const int* in_sizes, int n_in,
                              void* d_out, int out_size, void* d_ws, size_t ws_size,
                              hipStream_t stream) {
  const float* x  = (const float*)d_in[0];
  const int*   xc = (const int*)d_in[1];
  const int*   yc = (const int*)d_in[2];
  float* outp = (float*)d_out;

  dim3 grid(1024, SEGS);   // (patch, channel segment)
  patch_extract<<<grid, 256, 0, stream>>>(x, xc, yc, outp);
}

// Round 5
// 64.055 us; speedup vs baseline: 1.0165x; 1.0165x over previous
//
#include <hip/hip_runtime.h>

// PatchExtractor: B=64, C=128, H=W=64, M=16, n=15. Bit-exact reformulation:
//   ix = y_cord + j - 7, iy = x_cord + i - 7   (reference swaps x/y coords)
//   valid = (0<=ix<64) && (0<=iy<64)
//   out[p][c][i][j] = valid ? x[b][c][iy][ix] : 0       for c in [0,128)
//   in_bounds (c=128) = valid minus reciprocal-multiply boundary flips:
//     flip iff idx==63 && coord<=62 (per axis)  [XLA lowers /63 to *fl32(1/63);
//     csn error +2.0..2.2 ulp for coord in 56..62 pushes grid past +1.0]
// Round-4 was correct but latency-bound (VGPR=8, one load in flight, scalar
// stores, 3.2 TB/s = 51% of ceiling). This version: flat quad decomposition,
// 4 independent gathers per thread + one aligned float4 store.

constexpr int NP    = 15;
constexpr int NPOS  = NP * NP;          // 225
constexpr int CH    = 128;
constexpr int HH    = 64, WW = 64;
constexpr int PLANE = HH * WW;          // 4096
constexpr unsigned PER_PATCH = (CH + 1) * NPOS;        // 29025
constexpr unsigned TOTAL     = 1024u * PER_PATCH;      // 29,721,600
constexpr unsigned TOTALQ    = TOTAL / 4u;             // 7,430,400 (exact)

__global__ __launch_bounds__(256)
void patch_gather4(const float* __restrict__ x,
                   const int* __restrict__ xcord,
                   const int* __restrict__ ycord,
                   float* __restrict__ out) {
  const unsigned q = blockIdx.x * 256u + threadIdx.x;   // one quad per thread
  if (q >= TOTALQ) return;
  const unsigned e0 = q * 4u;

  float vals[4];
#pragma unroll
  for (int u = 0; u < 4; ++u) {
    const unsigned e   = e0 + (unsigned)u;
    const unsigned p   = e / PER_PATCH;          // magic-mul
    const unsigned r   = e - p * PER_PATCH;
    const unsigned ch  = r / NPOS;               // magic-mul
    const unsigned pos = r - ch * NPOS;
    const unsigned i   = pos / NP;               // magic-mul
    const unsigned j   = pos - i * NP;
    const int xs = xcord[p];                     // 4KB arrays: L1-resident
    const int ys = ycord[p];
    const int ix = ys + (int)j - 7;              // x index from y_cord (quirk)
    const int iy = xs + (int)i - 7;              // y index from x_cord
    const bool v = ((unsigned)ix < (unsigned)WW) && ((unsigned)iy < (unsigned)HH);
    if (ch == CH) {
      const bool xflip = (ix == WW - 1) && (ys < WW - 1);
      const bool yflip = (iy == HH - 1) && (xs < HH - 1);
      vals[u] = (v && !xflip && !yflip) ? 1.0f : 0.0f;
    } else {
      const unsigned b = p >> 4;                 // M = 16
      vals[u] = v ? x[(size_t)(b * CH + ch) * PLANE + (unsigned)(iy * WW + ix)]
                  : 0.0f;
    }
  }

  float4 o;
  o.x = vals[0]; o.y = vals[1]; o.z = vals[2]; o.w = vals[3];
  *reinterpret_cast<float4*>(out + (size_t)e0) = o;   // 16B-aligned (e0 % 4 == 0)
}

extern "C" void kernel_launch(void* const* d_in, const int* in_sizes, int n_in,
                              void* d_out, int out_size, void* d_ws, size_t ws_size,
                              hipStream_t stream) {
  const float* x  = (const float*)d_in[0];
  const int*   xc = (const int*)d_in[1];
  const int*   yc = (const int*)d_in[2];
  float* outp = (float*)d_out;

  const unsigned blocks = (TOTALQ + 255u) / 256u;   // 29,025 blocks
  patch_gather4<<<blocks, 256, 0, stream>>>(x, xc, yc, outp);
}

// Round 6
// 50.767 us; speedup vs baseline: 1.2826x; 1.2617x over previous
//
#include <hip/hip_runtime.h>

// PatchExtractor: B=64, C=128, H=W=64, M=16, n=15. Bit-exact reformulation:
//   ix = y_cord + j - 7, iy = x_cord + i - 7   (reference swaps x/y coords)
//   valid = (0<=ix<64) && (0<=iy<64)
//   out[p][c][i][j] = valid ? x[b][c][iy][ix] : 0       for c in [0,128)
//   in_bounds (c=128) = valid minus reciprocal-multiply boundary flips:
//     flip iff idx==63 && coord<=62 (per axis)  [XLA lowers /63 -> *fl32(1/63);
//     csn error +2.0..2.2 ulp for coord 56..62 pushes grid past +1.0 at idx 63]
//
// R4 (per-patch gather) and R5 (flat quad gather) both hit 64 us = 63% of
// streaming ceiling with minimal traffic -> read-side DRAM locality is the
// suspect. This version streams x planes SEQUENTIALLY through LDS (reads
// become pure unit-stride float4 copy) and cuts patches out of LDS.

constexpr int NP    = 15;
constexpr int NPOS  = NP * NP;          // 225
constexpr int CH    = 128;
constexpr int HH    = 64, WW = 64;
constexpr int PLANE = HH * WW;          // 4096
constexpr int CG    = 2;                // channels staged per block (32 KB LDS)
constexpr int NCG   = CH / CG;          // 64 channel groups
constexpr int MPB   = 16;               // patches (units) per batch
constexpr unsigned PER_PATCH = (CH + 1) * NPOS;   // 29025

__global__ __launch_bounds__(256)
void patch_stage(const float* __restrict__ x,
                 const int* __restrict__ xcord,
                 const int* __restrict__ ycord,
                 float* __restrict__ out) {
  const int cg = blockIdx.x;            // 0..63 = channel groups, 64 = in_bounds
  const int b  = blockIdx.y;            // batch
  const int t  = threadIdx.x;

  __shared__ int   sx[MPB], sy[MPB];
  __shared__ float s[CG * PLANE];       // 32 KB plane stage

  if (t < MPB) { sx[t] = xcord[b * MPB + t]; sy[t] = ycord[b * MPB + t]; }

  if (cg == NCG) {
    // in_bounds channel: no x data needed
    __syncthreads();
    for (int e = t; e < MPB * NPOS; e += 256) {
      const int p   = e / NPOS;
      const int pos = e - p * NPOS;
      const int i  = pos / NP;
      const int j  = pos - i * NP;
      const int xs = sx[p], ys = sy[p];
      const int ix = ys + j - 7;        // x index from y_cord (reference quirk)
      const int iy = xs + i - 7;
      const bool v = ((unsigned)ix < (unsigned)WW) && ((unsigned)iy < (unsigned)HH);
      const bool xflip = (ix == WW - 1) && (ys < WW - 1);
      const bool yflip = (iy == HH - 1) && (xs < HH - 1);
      out[(size_t)(b * MPB + p) * PER_PATCH + (size_t)CH * NPOS + pos] =
          (v && !xflip && !yflip) ? 1.0f : 0.0f;
    }
    return;
  }

  // Phase 1: stream CG contiguous channel planes into LDS (pure sequential read)
  const float* __restrict__ src = x + ((size_t)b * CH + cg * CG) * PLANE;
  for (int k = t; k < CG * PLANE / 4; k += 256)
    reinterpret_cast<float4*>(s)[k] = reinterpret_cast<const float4*>(src)[k];
  __syncthreads();

  // Phase 2: cut patches out of LDS; stores are contiguous per (patch, cg) chunk
  for (int e = t; e < MPB * CG * NPOS; e += 256) {
    const int p   = e / (CG * NPOS);    // magic-mul div by 450
    const int r   = e - p * (CG * NPOS);
    const int ch  = r / NPOS;           // magic-mul div by 225
    const int pos = r - ch * NPOS;
    const int i  = pos / NP;
    const int j  = pos - i * NP;
    const int xs = sx[p], ys = sy[p];
    const int ix = ys + j - 7;
    const int iy = xs + i - 7;
    const bool v = ((unsigned)ix < (unsigned)WW) && ((unsigned)iy < (unsigned)HH);
    const float val = v ? s[ch * PLANE + iy * WW + ix] : 0.0f;
    out[(size_t)(b * MPB + p) * PER_PATCH + (size_t)(cg * CG) * NPOS + r] = val;
  }
}

extern "C" void kernel_launch(void* const* d_in, const int* in_sizes, int n_in,
                              void* d_out, int out_size, void* d_ws, size_t ws_size,
                              hipStream_t stream) {
  const float* x  = (const float*)d_in[0];
  const int*   xc = (const int*)d_in[1];
  const int*   yc = (const int*)d_in[2];
  float* outp = (float*)d_out;

  dim3 grid(NCG + 1, 64);   // (channel group | in_bounds, batch)
  patch_stage<<<grid, 256, 0, stream>>>(x, xc, yc, outp);
}

// Round 7
// 46.913 us; speedup vs baseline: 1.3879x; 1.0822x over previous
//
#include <hip/hip_runtime.h>

// PatchExtractor: B=64, C=128, H=W=64, M=16, n=15. Bit-exact reformulation:
//   ix = y_cord + j - 7, iy = x_cord + i - 7   (reference swaps x/y coords)
//   valid = (0<=ix<64) && (0<=iy<64)
//   out[p][c][i][j] = valid ? x[b][c][iy][ix] : 0       for c in [0,128)
//   in_bounds (c=128) = valid minus reciprocal-multiply boundary flips:
//     flip iff idx==63 && coord<=62 (per axis)  [XLA lowers /63 -> *fl32(1/63);
//     csn error +2.0..2.2 ulp for coord 56..62 pushes grid past +1.0 at idx 63]
//
// R6 (plane staging, CG=2) = 50.8us but 1.64M LDS bank conflicts (row stride
// 64 floats == 0 mod 32 banks -> bank independent of row, 15 banks used,
// ~4.3-way) and occupancy 36% (33KB LDS, 4 blocks/CU). This version:
//   - CG=1 (16.5KB LDS -> 8 blocks/CU resident)
//   - swizzled plane: float4 col c4 of row iy stored at (c4 + 2*iy) & 15
//     -> all residual conflicts <=2-way (free per m136)

constexpr int NP    = 15;
constexpr int NPOS  = NP * NP;          // 225
constexpr int CH    = 128;
constexpr int HH    = 64, WW = 64;
constexpr int PLANE = HH * WW;          // 4096
constexpr int MPB   = 16;               // patches (units) per batch
constexpr unsigned PER_PATCH = (CH + 1) * NPOS;   // 29025

__global__ __launch_bounds__(256)
void patch_swz(const float* __restrict__ x,
               const int* __restrict__ xcord,
               const int* __restrict__ ycord,
               float* __restrict__ out) {
  const int cg = blockIdx.x;            // 0..127 = channel, 128 = in_bounds
  const int b  = blockIdx.y;            // batch
  const int t  = threadIdx.x;

  __shared__ int    sx[MPB], sy[MPB];
  __shared__ float4 s4[HH * (WW / 4)];  // 16 KB swizzled plane

  if (t < MPB) { sx[t] = xcord[b * MPB + t]; sy[t] = ycord[b * MPB + t]; }

  if (cg == CH) {
    // in_bounds channel: no x data needed
    __syncthreads();
    for (int e = t; e < MPB * NPOS; e += 256) {
      const int p   = e / NPOS;
      const int pos = e - p * NPOS;
      const int i  = pos / NP;
      const int j  = pos - i * NP;
      const int xs = sx[p], ys = sy[p];
      const int ix = ys + j - 7;        // x index from y_cord (reference quirk)
      const int iy = xs + i - 7;
      const bool v = ((unsigned)ix < (unsigned)WW) && ((unsigned)iy < (unsigned)HH);
      const bool xflip = (ix == WW - 1) && (ys < WW - 1);
      const bool yflip = (iy == HH - 1) && (xs < HH - 1);
      out[(size_t)(b * MPB + p) * PER_PATCH + (size_t)CH * NPOS + pos] =
          (v && !xflip && !yflip) ? 1.0f : 0.0f;
    }
    return;
  }

  // Phase 1: stream one channel plane into LDS, swizzled (pure sequential read)
  const float4* __restrict__ src =
      reinterpret_cast<const float4*>(x + ((size_t)b * CH + cg) * PLANE);
#pragma unroll
  for (int k = t; k < PLANE / 4; k += 256) {
    const int row = k >> 4;             // iy
    const int c4  = k & 15;             // float4 column
    s4[(row << 4) + ((c4 + 2 * row) & 15)] = src[k];
  }
  __syncthreads();

  // Phase 2: cut patches out of LDS; stores contiguous per (patch, channel)
  const float* __restrict__ s = reinterpret_cast<const float*>(s4);
  const size_t outbase = (size_t)b * MPB * PER_PATCH + (size_t)cg * NPOS;
  for (int e = t; e < MPB * NPOS; e += 256) {
    const int p   = e / NPOS;           // magic-mul
    const int pos = e - p * NPOS;
    const int i  = pos / NP;            // magic-mul
    const int j  = pos - i * NP;
    const int xs = sx[p], ys = sy[p];
    const int ix = ys + j - 7;
    const int iy = xs + i - 7;
    const bool v = ((unsigned)ix < (unsigned)WW) && ((unsigned)iy < (unsigned)HH);
    float val = 0.0f;
    if (v) {
      const int c4 = ix >> 2, w = ix & 3;
      val = s[(iy << 6) + (((c4 + 2 * iy) & 15) << 2) + w];
    }
    out[outbase + (size_t)p * PER_PATCH + pos] = val;
  }
}

extern "C" void kernel_launch(void* const* d_in, const int* in_sizes, int n_in,
                              void* d_out, int out_size, void* d_ws, size_t ws_size,
                              hipStream_t stream) {
  const float* x  = (const float*)d_in[0];
  const int*   xc = (const int*)d_in[1];
  const int*   yc = (const int*)d_in[2];
  float* outp = (float*)d_out;

  dim3 grid(CH + 1, 64);   // (channel | in_bounds, batch)
  patch_swz<<<grid, 256, 0, stream>>>(x, xc, yc, outp);
}

// Round 8
// 46.351 us; speedup vs baseline: 1.4048x; 1.0121x over previous
//
#include <hip/hip_runtime.h>

// PatchExtractor: B=64, C=128, H=W=64, M=16, n=15. Bit-exact reformulation:
//   ix = y_cord + j - 7, iy = x_cord + i - 7   (reference swaps x/y coords)
//   valid = (0<=ix<64) && (0<=iy<64)
//   out[p][c][i][j] = valid ? x[b][c][iy][ix] : 0       for c in [0,128)
//   in_bounds (c=128) = valid minus reciprocal-multiply boundary flips:
//     flip iff idx==63 && coord<=62 (per axis)  [XLA lowers /63 -> *fl32(1/63);
//     csn error +2.0..2.2 ulp for coord 56..62 pushes grid past +1.0 at idx 63]
//
// R7: 46.9us, occupancy 73%, but scalar 4B stores + ~28 VALU/element cap the
// write stream at 2.5 TB/s (combined 3.9 vs 6.9 demonstrated). This version:
//   - wave-per-chunk: one wave emits a whole 225-float (patch,channel) chunk
//     as head-scalars + aligned float4 body + tail-scalars (4x fewer stores)
//   - swizzle fixed to (c4 + iy) & 15: rows 4 apart now hit disjoint bank
//     groups (old 2*iy collapsed mod 8); residual aliasing is 2-way = free.

constexpr int NP    = 15;
constexpr int NPOS  = NP * NP;          // 225
constexpr int CH    = 128;
constexpr int HH    = 64, WW = 64;
constexpr int PLANE = HH * WW;          // 4096
constexpr int MPB   = 16;               // patches (units) per batch
constexpr unsigned PER_PATCH = (CH + 1) * NPOS;   // 29025

__device__ __forceinline__ float sample(const float* __restrict__ s,
                                        int xs, int ys, int pos) {
  const int i  = pos / NP;              // magic-mul
  const int j  = pos - i * NP;
  const int ix = ys + j - 7;            // x index from y_cord (reference quirk)
  const int iy = xs + i - 7;
  if (((unsigned)ix < (unsigned)WW) && ((unsigned)iy < (unsigned)HH)) {
    const int c4 = ix >> 2, w = ix & 3;
    return s[(iy << 6) + ((((c4 + iy) & 15)) << 2) + w];
  }
  return 0.0f;
}

__global__ __launch_bounds__(256)
void patch_swz4(const float* __restrict__ x,
                const int* __restrict__ xcord,
                const int* __restrict__ ycord,
                float* __restrict__ out) {
  const int cg = blockIdx.x;            // 0..127 = channel, 128 = in_bounds
  const int b  = blockIdx.y;            // batch
  const int t  = threadIdx.x;

  __shared__ int    sx[MPB], sy[MPB];
  __shared__ float4 s4[HH * (WW / 4)];  // 16 KB swizzled plane

  if (t < MPB) { sx[t] = xcord[b * MPB + t]; sy[t] = ycord[b * MPB + t]; }

  if (cg == CH) {
    // in_bounds channel: no x data needed (0.8% of work, keep scalar)
    __syncthreads();
    for (int e = t; e < MPB * NPOS; e += 256) {
      const int p   = e / NPOS;
      const int pos = e - p * NPOS;
      const int i  = pos / NP;
      const int j  = pos - i * NP;
      const int xs = sx[p], ys = sy[p];
      const int ix = ys + j - 7;
      const int iy = xs + i - 7;
      const bool v = ((unsigned)ix < (unsigned)WW) && ((unsigned)iy < (unsigned)HH);
      const bool xflip = (ix == WW - 1) && (ys < WW - 1);
      const bool yflip = (iy == HH - 1) && (xs < HH - 1);
      out[(size_t)(b * MPB + p) * PER_PATCH + (size_t)CH * NPOS + pos] =
          (v && !xflip && !yflip) ? 1.0f : 0.0f;
    }
    return;
  }

  // Phase 1: stream one channel plane into LDS, swizzled (pure sequential read)
  const float4* __restrict__ src =
      reinterpret_cast<const float4*>(x + ((size_t)b * CH + cg) * PLANE);
#pragma unroll
  for (int k = t; k < PLANE / 4; k += 256) {
    const int row = k >> 4;             // iy
    const int c4  = k & 15;             // float4 column
    s4[(row << 4) + ((c4 + row) & 15)] = src[k];
  }
  __syncthreads();

  // Phase 2: one wave per (patch, channel) chunk of 225 consecutive floats.
  const float* __restrict__ s = reinterpret_cast<const float*>(s4);
  const int wv   = t >> 6;              // wave 0..3
  const int lane = t & 63;
  for (int p = wv; p < MPB; p += 4) {
    const int xs = sx[p], ys = sy[p];
    const size_t Bp = (size_t)(b * MPB + p) * PER_PATCH + (size_t)cg * NPOS;
    const int h  = (4 - (int)(Bp & 3)) & 3;       // head scalars to align
    const int nq = (NPOS - h) >> 2;               // aligned float4 count (55/56)
    const int r  = NPOS - h - 4 * nq;             // tail scalars

    if (lane < h)
      out[Bp + lane] = sample(s, xs, ys, lane);

    if (lane < nq) {
      const int p0 = h + 4 * lane;
      float4 o;
      o.x = sample(s, xs, ys, p0);
      o.y = sample(s, xs, ys, p0 + 1);
      o.z = sample(s, xs, ys, p0 + 2);
      o.w = sample(s, xs, ys, p0 + 3);
      *reinterpret_cast<float4*>(out + Bp + h + 4 * (size_t)lane) = o;
    }

    if (lane < r) {
      const int pt = h + 4 * nq + lane;
      out[Bp + pt] = sample(s, xs, ys, pt);
    }
  }
}

extern "C" void kernel_launch(void* const* d_in, const int* in_sizes, int n_in,
                              void* d_out, int out_size, void* d_ws, size_t ws_size,
                              hipStream_t stream) {
  const float* x  = (const float*)d_in[0];
  const int*   xc = (const int*)d_in[1];
  const int*   yc = (const int*)d_in[2];
  float* outp = (float*)d_out;

  dim3 grid(CH + 1, 64);   // (channel | in_bounds, batch)
  patch_swz4<<<grid, 256, 0, stream>>>(x, xc, yc, outp);
}

// Round 9
// 44.879 us; speedup vs baseline: 1.4508x; 1.0328x over previous
//
#include <hip/hip_runtime.h>

// PatchExtractor: B=64, C=128, H=W=64, M=16, n=15. Bit-exact reformulation:
//   ix = y_cord + j - 7, iy = x_cord + i - 7   (reference swaps x/y coords)
//   valid = (0<=ix<64) && (0<=iy<64)
//   out[p][c][i][j] = valid ? x[b][c][iy][ix] : 0       for c in [0,128)
//   in_bounds (c=128) = valid minus reciprocal-multiply boundary flips:
//     flip iff idx==63 && coord<=62 (per axis)  [XLA lowers /63 -> *fl32(1/63);
//     csn error +2.0..2.2 ulp for coord 56..62 pushes grid past +1.0 at idx 63]
//
// R8: 46.4us, VGPR=16 -> phase-1 plane copy serialized (one float4 in flight,
// ~4x900cy exposed HBM latency per wave). This version stages the plane with
// __builtin_amdgcn_global_load_lds width=16 (direct HBM->LDS DMA, no VGPR
// roundtrip, all 4 loads in flight). LDS stays LINEAR; the bank-conflict
// swizzle is applied by pre-permuting the per-lane GLOBAL source address
// (inverse of the phase-2 read swizzle): LDS slot (row,c4') <- global col
// (c4'-row)&15. Within-row permutation keeps reads fully sector-coalesced.

constexpr int NP    = 15;
constexpr int NPOS  = NP * NP;          // 225
constexpr int CH    = 128;
constexpr int HH    = 64, WW = 64;
constexpr int PLANE = HH * WW;          // 4096
constexpr int MPB   = 16;               // patches (units) per batch
constexpr unsigned PER_PATCH = (CH + 1) * NPOS;   // 29025

__device__ __forceinline__ float sample(const float* __restrict__ s,
                                        int xs, int ys, int pos) {
  const int i  = pos / NP;              // magic-mul
  const int j  = pos - i * NP;
  const int ix = ys + j - 7;            // x index from y_cord (reference quirk)
  const int iy = xs + i - 7;
  if (((unsigned)ix < (unsigned)WW) && ((unsigned)iy < (unsigned)HH)) {
    const int c4 = ix >> 2, w = ix & 3;
    return s[(iy << 6) + (((c4 + iy) & 15) << 2) + w];
  }
  return 0.0f;
}

__global__ __launch_bounds__(256)
void patch_dma(const float* __restrict__ x,
               const int* __restrict__ xcord,
               const int* __restrict__ ycord,
               float* __restrict__ out) {
  const int cg = blockIdx.x;            // 0..127 = channel, 128 = in_bounds
  const int b  = blockIdx.y;            // batch
  const int t  = threadIdx.x;

  __shared__ int    sx[MPB], sy[MPB];
  __shared__ float4 s4[HH * (WW / 4)];  // 16 KB plane (linear; swizzle via src)

  if (t < MPB) { sx[t] = xcord[b * MPB + t]; sy[t] = ycord[b * MPB + t]; }

  if (cg == CH) {
    // in_bounds channel: no x data needed (0.8% of work)
    __syncthreads();
    for (int e = t; e < MPB * NPOS; e += 256) {
      const int p   = e / NPOS;
      const int pos = e - p * NPOS;
      const int i  = pos / NP;
      const int j  = pos - i * NP;
      const int xs = sx[p], ys = sy[p];
      const int ix = ys + j - 7;
      const int iy = xs + i - 7;
      const bool v = ((unsigned)ix < (unsigned)WW) && ((unsigned)iy < (unsigned)HH);
      const bool xflip = (ix == WW - 1) && (ys < WW - 1);
      const bool yflip = (iy == HH - 1) && (xs < HH - 1);
      out[(size_t)(b * MPB + p) * PER_PATCH + (size_t)CH * NPOS + pos] =
          (v && !xflip && !yflip) ? 1.0f : 0.0f;
    }
    return;
  }

  // Phase 1: DMA one channel plane HBM->LDS, 4 x global_load_lds_dwordx4 per
  // thread, all in flight; source pre-permuted so LDS slot (row,c4') holds
  // global float4 column (c4'-row)&15 of row.
  const float4* __restrict__ src =
      reinterpret_cast<const float4*>(x + ((size_t)b * CH + cg) * PLANE);
#pragma unroll
  for (int k = 0; k < 4; ++k) {
    const int slot  = k * 256 + t;            // LDS float4 slot this lane fills
    const int row   = slot >> 4;
    const int c4p   = slot & 15;
    const int srcf4 = (row << 4) + ((c4p - row) & 15);
    // wave-uniform LDS base (lane*16B added by HW)
    float4* ldsbase = &s4[k * 256 + (t & 192)];
    __builtin_amdgcn_global_load_lds(
        (const __attribute__((address_space(1))) void*)(src + srcf4),
        (__attribute__((address_space(3))) void*)ldsbase,
        16, 0, 0);
  }
  __syncthreads();   // drains vmcnt

  // Phase 2: one wave per (patch, channel) chunk of 225 consecutive floats.
  const float* __restrict__ s = reinterpret_cast<const float*>(s4);
  const int wv   = t >> 6;              // wave 0..3
  const int lane = t & 63;
  for (int p = wv; p < MPB; p += 4) {
    const int xs = sx[p], ys = sy[p];
    const size_t Bp = (size_t)(b * MPB + p) * PER_PATCH + (size_t)cg * NPOS;
    const int h  = (4 - (int)(Bp & 3)) & 3;       // head scalars to align
    const int nq = (NPOS - h) >> 2;               // aligned float4 count (55/56)
    const int r  = NPOS - h - 4 * nq;             // tail scalars

    if (lane < h)
      out[Bp + lane] = sample(s, xs, ys, lane);

    if (lane < nq) {
      const int p0 = h + 4 * lane;
      float4 o;
      o.x = sample(s, xs, ys, p0);
      o.y = sample(s, xs, ys, p0 + 1);
      o.z = sample(s, xs, ys, p0 + 2);
      o.w = sample(s, xs, ys, p0 + 3);
      *reinterpret_cast<float4*>(out + Bp + h + 4 * (size_t)lane) = o;
    }

    if (lane < r) {
      const int pt = h + 4 * nq + lane;
      out[Bp + pt] = sample(s, xs, ys, pt);
    }
  }
}

extern "C" void kernel_launch(void* const* d_in, const int* in_sizes, int n_in,
                              void* d_out, int out_size, void* d_ws, size_t ws_size,
                              hipStream_t stream) {
  const float* x  = (const float*)d_in[0];
  const int*   xc = (const int*)d_in[1];
  const int*   yc = (const int*)d_in[2];
  float* outp = (float*)d_out;

  dim3 grid(CH + 1, 64);   // (channel | in_bounds, batch)
  patch_dma<<<grid, 256, 0, stream>>>(x, xc, yc, outp);
}